// Round 1
// baseline (2513.507 us; speedup 1.0000x reference)
//
#include <hip/hip_runtime.h>
#include <math.h>

#define L 8
#define N 32768
#define H 404
#define D 128
#define F 532
#define FPAD 544          // F padded up to multiple of 16 (rows 532..543 zeroed)
#define BN 256            // neighbor rows per block in the big kernel
#define NCHUNK (N / BN)   // 128

// workspace layout (float offsets)
#define WS_WT      0                       // 544*128 = 69632  (W_fa^T, zero-padded)
#define WS_HMAXK   (WS_WT + FPAD * D)      // 8*128 uint keys
#define WS_HSEL    (WS_HMAXK + L * D)      // 7*128
#define WS_GI      (WS_HSEL + (L - 1) * D) // 8*1212
#define WS_HBUF    (WS_GI + L * 3 * H)     // 2*404
#define WS_V       (WS_HBUF + 2 * H)       // 532
#define WS_SCAL    (WS_V + F)              // c, M, S, spare
#define WS_PM      (WS_SCAL + 4)           // 64
#define WS_PS      (WS_PM + 64)            // 64
#define WS_LOGITS  (WS_PS + 64)            // 32769

__device__ __forceinline__ unsigned encf(float f) {
    unsigned u = __float_as_uint(f);
    return (u & 0x80000000u) ? ~u : (u | 0x80000000u);
}
__device__ __forceinline__ float decf(unsigned u) {
    unsigned b = (u & 0x80000000u) ? (u ^ 0x80000000u) : ~u;
    return __uint_as_float(b);
}
__device__ __forceinline__ float sigmoidf_(float x) {
    return 1.0f / (1.0f + __expf(-x));
}

// ---- K1: transpose W_fa (D x F) -> Wt (FPAD x D), zero padding rows ----
__global__ void k_wt(const float* __restrict__ Wfa, float* __restrict__ wt) {
    int i = blockIdx.x * 256 + threadIdx.x;
    if (i >= FPAD * D) return;
    int f = i / D, d = i % D;
    wt[i] = (f < F) ? Wfa[d * F + f] : 0.0f;
}

// ---- K0: init hmax keys ----
__global__ void k_init(unsigned* __restrict__ keys) {
    int i = blockIdx.x * 256 + threadIdx.x;
    if (i < L * D) keys[i] = 0u;
}

// ---- K2: big einsum + column max + selected-row extraction ----
// one thread = one neighbor row; acc[128] in VGPRs; W read via uniform (scalar) loads
__global__ __launch_bounds__(256, 1)
void k_big(const float* __restrict__ nb, const float* __restrict__ wt,
           const float* __restrict__ bfa, const int* __restrict__ aid,
           unsigned* __restrict__ hmaxk, float* __restrict__ hsel) {
    int bid = blockIdx.x;
    int l = bid / NCHUNK, c = bid % NCHUNK;
    int tid = threadIdx.x;
    long nrow = (long)c * BN + tid;   // row index within this l
    const float* xbase = nb + ((long)l * N + (long)c * BN) * F;

    __shared__ float xs[BN][17];

    float acc[D];
#pragma unroll
    for (int d = 0; d < D; ++d) acc[d] = bfa[d];

    for (int fc = 0; fc < FPAD; fc += 16) {
        __syncthreads();
        // coalesced stage of 256 rows x 16 f
        for (int k = 0; k < 16; ++k) {
            int i = tid + k * 256;
            int r = i >> 4, f = i & 15;
            int fg = fc + f;
            xs[r][f] = (fg < F) ? xbase[(long)r * F + fg] : 0.0f;
        }
        __syncthreads();
#pragma unroll 4
        for (int f = 0; f < 16; ++f) {
            float xv = xs[tid][f];
            const float* wrow = wt + (fc + f) * D;   // uniform address -> s_load
#pragma unroll
            for (int d = 0; d < D; ++d) acc[d] = fmaf(xv, wrow[d], acc[d]);
        }
    }

    // selected action row (l < 7)
    if (l < L - 1 && (int)nrow == aid[l]) {
#pragma unroll
        for (int d = 0; d < D; ++d) hsel[l * D + d] = acc[d];
    }

    // column max: wave shuffle reduce, then cross-wave via LDS, then atomicMax
    __shared__ float wmax[4][D];
    int lane = tid & 63, wid = tid >> 6;
#pragma unroll
    for (int d = 0; d < D; ++d) {
        float m = acc[d];
        for (int off = 1; off < 64; off <<= 1)
            m = fmaxf(m, __shfl_xor(m, off, 64));
        if (lane == 0) wmax[wid][d] = m;
    }
    __syncthreads();
    if (tid < D) {
        float m = fmaxf(fmaxf(wmax[0][tid], wmax[1][tid]),
                        fmaxf(wmax[2][tid], wmax[3][tid]));
        atomicMax(&hmaxk[l * D + tid], encf(m));
    }
}

// ---- K3: precompute gi for all 8 GRU steps ----
__global__ void k_gi(const float* __restrict__ Wih, const float* __restrict__ bih,
                     const float* __restrict__ pn, const unsigned* __restrict__ hmaxk,
                     const float* __restrict__ hsel, float* __restrict__ gi) {
    int i = blockIdx.x * 256 + threadIdx.x;
    if (i >= L * 3 * H) return;
    int t = i / (3 * H), row = i % (3 * H);
    float s = bih[row];
    const float* wr = Wih + (long)row * 3 * D;
    for (int k = 0; k < 3 * D; ++k) {
        float x;
        if (t == 0) {
            x = (k < 2 * D) ? 0.0f : pn[k - 2 * D];
        } else {
            if (k < D)            x = decf(hmaxk[(t - 1) * D + k]);
            else if (k < 2 * D)   x = hsel[(t - 1) * D + (k - D)];
            else                  x = pn[t * D + (k - 2 * D)];
        }
        s = fmaf(x, wr[k], s);
    }
    gi[i] = s;
}

// ---- K4: one GRU step; one wave per hidden index ----
__global__ void k_step(const float* __restrict__ Whh, const float* __restrict__ bhh,
                       const float* __restrict__ gi_t, const float* __restrict__ hin,
                       float* __restrict__ hout) {
    int wave = blockIdx.x * 4 + (threadIdx.x >> 6);
    int lane = threadIdx.x & 63;
    if (wave >= H) return;
    int j = wave;
    float pr = 0.f, pz = 0.f, pnn = 0.f;
    for (int i = lane; i < H; i += 64) {
        float hv = hin[i];
        pr  = fmaf(Whh[(long)j * H + i], hv, pr);
        pz  = fmaf(Whh[(long)(H + j) * H + i], hv, pz);
        pnn = fmaf(Whh[(long)(2 * H + j) * H + i], hv, pnn);
    }
    for (int off = 1; off < 64; off <<= 1) {
        pr  += __shfl_xor(pr, off, 64);
        pz  += __shfl_xor(pz, off, 64);
        pnn += __shfl_xor(pnn, off, 64);
    }
    if (lane == 0) {
        float r = sigmoidf_(gi_t[j] + pr + bhh[j]);
        float z = sigmoidf_(gi_t[H + j] + pz + bhh[H + j]);
        float nn = tanhf(gi_t[2 * H + j] + r * (pnn + bhh[2 * H + j]));
        hout[j] = (1.0f - z) * nn + z * hin[j];
    }
}

// ---- K5: hSt, u0, v = W_fa^T hSt, c = hSt.b_fa ----
__global__ void k_final(const float* __restrict__ qt, const float* __restrict__ Wfs,
                        const float* __restrict__ bfs, const float* __restrict__ Wfa,
                        const float* __restrict__ bfa, const float* __restrict__ Wfp,
                        const float* __restrict__ bfp, const unsigned* __restrict__ hmaxk,
                        float* __restrict__ v, float* __restrict__ scal,
                        float* __restrict__ logits) {
    __shared__ float hs[D];
    int tid = threadIdx.x;
    if (tid < D) {
        float s = bfs[tid];
        for (int j = 0; j < H; ++j) s = fmaf(qt[j], Wfs[tid * H + j], s);
        hs[tid] = s;
    }
    __syncthreads();
    if (tid < F) {
        float s = 0.f;
        for (int d = 0; d < D; ++d) s = fmaf(hs[d], Wfa[d * F + tid], s);
        v[tid] = s;
    } else if (tid == F) {
        float s = bfp[0];
        for (int d = 0; d < D; ++d) s = fmaf(hs[d], Wfp[d], s);
        for (int d = 0; d < D; ++d) s = fmaf(decf(hmaxk[(L - 1) * D + d]), Wfp[D + d], s);
        logits[0] = s;
    } else if (tid == F + 1) {
        float s = 0.f;
        for (int d = 0; d < D; ++d) s = fmaf(hs[d], bfa[d], s);
        scal[0] = s;
    }
}

// ---- K6: uks logits; one wave per neighbor row of hop 7 ----
__global__ void k_uks(const float* __restrict__ nb7, const float* __restrict__ v,
                      const float* __restrict__ scal, float* __restrict__ logits) {
    long n = (long)blockIdx.x * 4 + (threadIdx.x >> 6);
    int lane = threadIdx.x & 63;
    const float* row = nb7 + n * F;
    float s = 0.f;
    for (int f = lane; f < F; f += 64) s = fmaf(v[f], row[f], s);
    for (int off = 1; off < 64; off <<= 1) s += __shfl_xor(s, off, 64);
    if (lane == 0) logits[1 + n] = s + scal[0];
}

// ---- K7/K8/K9: softmax over 32769 ----
__global__ void k_sm1(const float* __restrict__ logits, float* __restrict__ pm,
                      float* __restrict__ ps) {
    int bid = blockIdx.x, tid = threadIdx.x;
    int start = bid * 513;
    int stop = min(start + 513, N + 1);
    float m = -3.4e38f, s = 0.f;
    for (int i = start + tid; i < stop; i += 256) {
        float x = logits[i];
        if (x > m) { s = s * __expf(m - x) + 1.0f; m = x; }
        else       { s += __expf(x - m); }
    }
    for (int off = 1; off < 64; off <<= 1) {
        float m2 = __shfl_xor(m, off, 64);
        float s2 = __shfl_xor(s, off, 64);
        float M = fmaxf(m, m2);
        s = s * __expf(m - M) + s2 * __expf(m2 - M);
        m = M;
    }
    __shared__ float sm[4], ss[4];
    int lane = tid & 63, wid = tid >> 6;
    if (lane == 0) { sm[wid] = m; ss[wid] = s; }
    __syncthreads();
    if (tid == 0) {
        float M = fmaxf(fmaxf(sm[0], sm[1]), fmaxf(sm[2], sm[3]));
        float S = ss[0] * __expf(sm[0] - M) + ss[1] * __expf(sm[1] - M) +
                  ss[2] * __expf(sm[2] - M) + ss[3] * __expf(sm[3] - M);
        pm[bid] = M; ps[bid] = S;
    }
}

__global__ void k_sm2(const float* __restrict__ pm, const float* __restrict__ ps,
                      float* __restrict__ scal) {
    int lane = threadIdx.x;
    float m = pm[lane], s = ps[lane];
    for (int off = 1; off < 64; off <<= 1) {
        float m2 = __shfl_xor(m, off, 64);
        float s2 = __shfl_xor(s, off, 64);
        float M = fmaxf(m, m2);
        s = s * __expf(m - M) + s2 * __expf(m2 - M);
        m = M;
    }
    if (lane == 0) { scal[1] = m; scal[2] = s; }
}

__global__ void k_sm3(const float* __restrict__ logits, const float* __restrict__ scal,
                      float* __restrict__ out) {
    int i = blockIdx.x * 256 + threadIdx.x;
    if (i <= N) out[i] = __expf(logits[i] - scal[1]) / scal[2];
}

extern "C" void kernel_launch(void* const* d_in, const int* in_sizes, int n_in,
                              void* d_out, int out_size, void* d_ws, size_t ws_size,
                              hipStream_t stream) {
    const float* query = (const float*)d_in[0];
    const float* pn    = (const float*)d_in[1];
    const float* nb    = (const float*)d_in[2];
    const int*   aid   = (const int*)d_in[3];
    const float* Wih   = (const float*)d_in[4];
    const float* Whh   = (const float*)d_in[5];
    const float* bih   = (const float*)d_in[6];
    const float* bhh   = (const float*)d_in[7];
    const float* Wfa   = (const float*)d_in[8];
    const float* bfa   = (const float*)d_in[9];
    const float* Wfs   = (const float*)d_in[10];
    const float* bfs   = (const float*)d_in[11];
    const float* Wfp   = (const float*)d_in[12];
    const float* bfp   = (const float*)d_in[13];

    float* ws = (float*)d_ws;
    float*    wt     = ws + WS_WT;
    unsigned* hmaxk  = (unsigned*)(ws + WS_HMAXK);
    float*    hsel   = ws + WS_HSEL;
    float*    gi     = ws + WS_GI;
    float*    hbuf   = ws + WS_HBUF;     // two H-sized buffers
    float*    v      = ws + WS_V;
    float*    scal   = ws + WS_SCAL;
    float*    pm     = ws + WS_PM;
    float*    psum   = ws + WS_PS;
    float*    logits = ws + WS_LOGITS;
    float*    out    = (float*)d_out;

    k_wt  <<<(FPAD * D + 255) / 256, 256, 0, stream>>>(Wfa, wt);
    k_init<<<(L * D + 255) / 256,  256, 0, stream>>>(hmaxk);
    k_big <<<L * NCHUNK, 256, 0, stream>>>(nb, wt, bfa, aid, hmaxk, hsel);
    k_gi  <<<(L * 3 * H + 255) / 256, 256, 0, stream>>>(Wih, bih, pn, hmaxk, hsel, gi);

    for (int t = 0; t < L; ++t) {
        const float* hin = (t == 0) ? query : (hbuf + ((t - 1) & 1) * H);
        float* hout = hbuf + (t & 1) * H;
        k_step<<<(H + 3) / 4, 256, 0, stream>>>(Whh, bhh, gi + t * 3 * H, hin, hout);
    }
    const float* qt = hbuf + ((L - 1) & 1) * H;   // hbuf[1]

    k_final<<<1, 576, 0, stream>>>(qt, Wfs, bfs, Wfa, bfa, Wfp, bfp, hmaxk, v, scal, logits);
    k_uks  <<<N / 4, 256, 0, stream>>>(nb + (long)(L - 1) * N * F, v, scal, logits);

    k_sm1<<<64, 256, 0, stream>>>(logits, pm, psum);
    k_sm2<<<1, 64, 0, stream>>>(pm, psum, scal);
    k_sm3<<<(N + 1 + 255) / 256, 256, 0, stream>>>(logits, scal, out);
}

// Round 2
// 456.963 us; speedup vs baseline: 5.5005x; 5.5005x over previous
//
#include <hip/hip_runtime.h>
#include <math.h>

#define L 8
#define N 32768
#define H 404
#define D 128
#define F 532
#define FP2 576           // F padded to 9*64 for BK=64 tiling (zeros beyond 532)
#define KT 9              // K-tiles of 64

typedef __attribute__((ext_vector_type(8))) short bf16x8;
typedef __attribute__((ext_vector_type(8))) short s16x8;
typedef __attribute__((ext_vector_type(4))) short s16x4;
typedef __attribute__((ext_vector_type(4))) float f32x4;

// workspace layout (float offsets)
#define WS_WHI     0                        // 128*576 ushort = 36864 floats
#define WS_WLO     (WS_WHI + 128*576/2)
#define WS_HMAXK   (WS_WLO + 128*576/2)     // 8*128 uint keys
#define WS_HSEL    (WS_HMAXK + L * D)       // 7*128
#define WS_GI      (WS_HSEL + (L - 1) * D)  // 8*1212
#define WS_HBUF    (WS_GI + L * 3 * H)      // 2*404
#define WS_V       (WS_HBUF + 2 * H)        // 532
#define WS_SCAL    (WS_V + F)               // c, M, S, spare
#define WS_PM      (WS_SCAL + 4)            // 64
#define WS_PS      (WS_PM + 64)             // 64
#define WS_LOGITS  (WS_PS + 64)             // 32769

__device__ __forceinline__ unsigned encf(float f) {
    unsigned u = __float_as_uint(f);
    return (u & 0x80000000u) ? ~u : (u | 0x80000000u);
}
__device__ __forceinline__ float decf(unsigned u) {
    unsigned b = (u & 0x80000000u) ? (u ^ 0x80000000u) : ~u;
    return __uint_as_float(b);
}
__device__ __forceinline__ float sigmoidf_(float x) {
    return 1.0f / (1.0f + __expf(-x));
}
__device__ __forceinline__ unsigned short f2bf(float f) {   // RNE
    unsigned u = __float_as_uint(f);
    u += 0x7FFFu + ((u >> 16) & 1u);
    return (unsigned short)(u >> 16);
}
__device__ __forceinline__ float bf2f(unsigned short h) {
    return __uint_as_float(((unsigned)h) << 16);
}

// ---- split W_fa (D x F) into hi/lo bf16, layout [d][FP2], zero-padded ----
__global__ void k_wbf(const float* __restrict__ Wfa, unsigned short* __restrict__ whi,
                      unsigned short* __restrict__ wlo) {
    int i = blockIdx.x * 256 + threadIdx.x;
    if (i >= 128 * FP2) return;
    int d = i / FP2, f = i % FP2;
    float v = (f < F) ? Wfa[d * F + f] : 0.0f;
    unsigned short h = f2bf(v);
    whi[i] = h;
    wlo[i] = f2bf(v - bf2f(h));
}

__global__ void k_init(unsigned* __restrict__ keys) {
    int i = blockIdx.x * 256 + threadIdx.x;
    if (i < L * D) keys[i] = 0u;   // enc(-NaN): below every finite encoding
}

// ---- big einsum via split-bf16 MFMA + column max + selected-row extraction ----
// grid 2048: l = bid>>8, 128-row chunk = bid&255. 4 waves, each 64x64 output.
__global__ __launch_bounds__(256, 2)
void k_big(const float* __restrict__ nb, const unsigned short* __restrict__ whi,
           const unsigned short* __restrict__ wlo, const float* __restrict__ bfa,
           const int* __restrict__ aid, unsigned* __restrict__ hmaxk,
           float* __restrict__ hsel) {
    __shared__ short As_hi[128 * 64];
    __shared__ short As_lo[128 * 64];
    __shared__ short Bs_hi[128 * 64];
    __shared__ short Bs_lo[128 * 64];

    const int bid = blockIdx.x;
    const int l_hop = bid >> 8;
    const int row0 = (bid & 255) * 128;
    const int tid = threadIdx.x;
    const int lane = tid & 63, w = tid >> 6;
    const int wm = w >> 1, wn = w & 1;
    const int lr = lane & 15, kg = lane >> 4;

    const float* xbase = nb + ((long)l_hop * N + row0) * F;

    // fragment read byte-offsets (XOR-swizzled)
    const int swz = (lr & 7) << 4;
    int abase[4], bbase[4];
#pragma unroll
    for (int m = 0; m < 4; ++m)
        abase[m] = (wm * 64 + m * 16 + lr) * 128 + ((kg * 16) ^ swz);
#pragma unroll
    for (int n = 0; n < 4; ++n)
        bbase[n] = (wn * 64 + n * 16 + lr) * 128 + ((kg * 16) ^ swz);

    // acc init = bias (broadcast down each column)
    f32x4 acc[4][4];
    float bv[4];
#pragma unroll
    for (int n = 0; n < 4; ++n) bv[n] = bfa[wn * 64 + n * 16 + lr];
#pragma unroll
    for (int m = 0; m < 4; ++m)
#pragma unroll
        for (int n = 0; n < 4; ++n) {
            acc[m][n][0] = bv[n]; acc[m][n][1] = bv[n];
            acc[m][n][2] = bv[n]; acc[m][n][3] = bv[n];
        }

    // A staging indices
    const int ar = tid >> 4, ac4 = tid & 15;          // row base, float4 idx
    const int awb = ((ac4 * 8) ^ 0);                  // pre-row byte (swizzle added per row)
    // B staging indices
    const int bd = tid >> 3, bc16 = tid & 7;

    for (int kt = 0; kt < KT; ++kt) {
        const int fc = kt * 64;
        __syncthreads();
        // ---- stage A: 128 rows x 64 f fp32 -> hi/lo bf16 ----
#pragma unroll
        for (int it = 0; it < 8; ++it) {
            int r = ar + it * 16;
            int fg = fc + ac4 * 4;
            float4 x = make_float4(0.f, 0.f, 0.f, 0.f);
            if (fg < F) x = *(const float4*)(xbase + (long)r * F + fg);
            unsigned short h0 = f2bf(x.x), h1 = f2bf(x.y), h2 = f2bf(x.z), h3 = f2bf(x.w);
            s16x4 hv = { (short)h0, (short)h1, (short)h2, (short)h3 };
            s16x4 lv = { (short)f2bf(x.x - bf2f(h0)), (short)f2bf(x.y - bf2f(h1)),
                         (short)f2bf(x.z - bf2f(h2)), (short)f2bf(x.w - bf2f(h3)) };
            int wb = r * 128 + ((ac4 * 8) ^ ((r & 7) << 4));
            *(s16x4*)((char*)As_hi + wb) = hv;
            *(s16x4*)((char*)As_lo + wb) = lv;
        }
        // ---- stage B: 128 d x 64 f bf16 hi/lo (pre-split) ----
#pragma unroll
        for (int it = 0; it < 4; ++it) {
            int dd = bd + it * 32;
            long so = (long)dd * FP2 + fc + bc16 * 8;
            int wb = dd * 128 + ((bc16 * 16) ^ ((dd & 7) << 4));
            *(s16x8*)((char*)Bs_hi + wb) = *(const s16x8*)(whi + so);
            *(s16x8*)((char*)Bs_lo + wb) = *(const s16x8*)(wlo + so);
        }
        __syncthreads();

        // ---- 2 K-steps of 32 ----
#pragma unroll
        for (int ks = 0; ks < 2; ++ks) {
            const int kx = ks << 6;
            bf16x8 ah[4], al[4], bh[4], bl[4];
#pragma unroll
            for (int m = 0; m < 4; ++m) {
                ah[m] = *(const bf16x8*)((char*)As_hi + (abase[m] ^ kx));
                al[m] = *(const bf16x8*)((char*)As_lo + (abase[m] ^ kx));
            }
#pragma unroll
            for (int n = 0; n < 4; ++n) {
                bh[n] = *(const bf16x8*)((char*)Bs_hi + (bbase[n] ^ kx));
                bl[n] = *(const bf16x8*)((char*)Bs_lo + (bbase[n] ^ kx));
            }
#pragma unroll
            for (int m = 0; m < 4; ++m)
#pragma unroll
                for (int n = 0; n < 4; ++n) {
                    acc[m][n] = __builtin_amdgcn_mfma_f32_16x16x32_bf16(ah[m], bh[n], acc[m][n], 0, 0, 0);
                    acc[m][n] = __builtin_amdgcn_mfma_f32_16x16x32_bf16(ah[m], bl[n], acc[m][n], 0, 0, 0);
                    acc[m][n] = __builtin_amdgcn_mfma_f32_16x16x32_bf16(al[m], bh[n], acc[m][n], 0, 0, 0);
                }
        }
    }

    __syncthreads();   // all LDS reads done; reuse As_hi for cross-wave max

    // selected-action row extraction (rare path, compile-time acc indexing)
    if (l_hop < L - 1) {
        int arow = aid[l_hop];
        int br = arow - row0;
        if (br >= 0 && br < 128 && (br >> 6) == wm && ((br >> 2) & 3) == kg) {
            int msel = (br >> 4) & 3, rsel = br & 3;
#pragma unroll
            for (int n = 0; n < 4; ++n) {
                float vsel = 0.f;
#pragma unroll
                for (int m = 0; m < 4; ++m)
#pragma unroll
                    for (int r = 0; r < 4; ++r)
                        if (m == msel && r == rsel) vsel = acc[m][n][r];
                hsel[l_hop * D + wn * 64 + n * 16 + lr] = vsel;
            }
        }
    }

    // column max: in-thread over m,r -> cross lane-group shfl -> cross-wave LDS -> atomic
    float cmax[4];
#pragma unroll
    for (int n = 0; n < 4; ++n) {
        float m0 = acc[0][n][0];
#pragma unroll
        for (int m = 0; m < 4; ++m)
#pragma unroll
            for (int r = 0; r < 4; ++r) m0 = fmaxf(m0, acc[m][n][r]);
        m0 = fmaxf(m0, __shfl_xor(m0, 16, 64));
        m0 = fmaxf(m0, __shfl_xor(m0, 32, 64));
        cmax[n] = m0;
    }
    float* wmaxp = (float*)As_hi;   // [2][128]
    if (kg == 0) {
#pragma unroll
        for (int n = 0; n < 4; ++n)
            wmaxp[wm * 128 + wn * 64 + n * 16 + lr] = cmax[n];
    }
    __syncthreads();
    if (tid < 128) {
        float mval = fmaxf(wmaxp[tid], wmaxp[128 + tid]);
        atomicMax(&hmaxk[l_hop * D + tid], encf(mval));
    }
}

// ---- precompute gi for all 8 GRU steps ----
__global__ void k_gi(const float* __restrict__ Wih, const float* __restrict__ bih,
                     const float* __restrict__ pn, const unsigned* __restrict__ hmaxk,
                     const float* __restrict__ hsel, float* __restrict__ gi) {
    int i = blockIdx.x * 256 + threadIdx.x;
    if (i >= L * 3 * H) return;
    int t = i / (3 * H), row = i % (3 * H);
    float s = bih[row];
    const float* wr = Wih + (long)row * 3 * D;
    for (int k = 0; k < 3 * D; ++k) {
        float x;
        if (t == 0) {
            x = (k < 2 * D) ? 0.0f : pn[k - 2 * D];
        } else {
            if (k < D)            x = decf(hmaxk[(t - 1) * D + k]);
            else if (k < 2 * D)   x = hsel[(t - 1) * D + (k - D)];
            else                  x = pn[t * D + (k - 2 * D)];
        }
        s = fmaf(x, wr[k], s);
    }
    gi[i] = s;
}

// ---- one GRU step; one wave per hidden index ----
__global__ void k_step(const float* __restrict__ Whh, const float* __restrict__ bhh,
                       const float* __restrict__ gi_t, const float* __restrict__ hin,
                       float* __restrict__ hout) {
    int wave = blockIdx.x * 4 + (threadIdx.x >> 6);
    int lane = threadIdx.x & 63;
    if (wave >= H) return;
    int j = wave;
    float pr = 0.f, pz = 0.f, pnn = 0.f;
    for (int i = lane; i < H; i += 64) {
        float hv = hin[i];
        pr  = fmaf(Whh[(long)j * H + i], hv, pr);
        pz  = fmaf(Whh[(long)(H + j) * H + i], hv, pz);
        pnn = fmaf(Whh[(long)(2 * H + j) * H + i], hv, pnn);
    }
    for (int off = 1; off < 64; off <<= 1) {
        pr  += __shfl_xor(pr, off, 64);
        pz  += __shfl_xor(pz, off, 64);
        pnn += __shfl_xor(pnn, off, 64);
    }
    if (lane == 0) {
        float r = sigmoidf_(gi_t[j] + pr + bhh[j]);
        float z = sigmoidf_(gi_t[H + j] + pz + bhh[H + j]);
        float nn = tanhf(gi_t[2 * H + j] + r * (pnn + bhh[2 * H + j]));
        hout[j] = (1.0f - z) * nn + z * hin[j];
    }
}

// ---- hSt, u0, v = W_fa^T hSt, c = hSt.b_fa ----
__global__ void k_final(const float* __restrict__ qt, const float* __restrict__ Wfs,
                        const float* __restrict__ bfs, const float* __restrict__ Wfa,
                        const float* __restrict__ bfa, const float* __restrict__ Wfp,
                        const float* __restrict__ bfp, const unsigned* __restrict__ hmaxk,
                        float* __restrict__ v, float* __restrict__ scal,
                        float* __restrict__ logits) {
    __shared__ float hs[D];
    int tid = threadIdx.x;
    if (tid < D) {
        float s = bfs[tid];
        for (int j = 0; j < H; ++j) s = fmaf(qt[j], Wfs[tid * H + j], s);
        hs[tid] = s;
    }
    __syncthreads();
    if (tid < F) {
        float s = 0.f;
        for (int d = 0; d < D; ++d) s = fmaf(hs[d], Wfa[d * F + tid], s);
        v[tid] = s;
    } else if (tid == F) {
        float s = bfp[0];
        for (int d = 0; d < D; ++d) s = fmaf(hs[d], Wfp[d], s);
        for (int d = 0; d < D; ++d) s = fmaf(decf(hmaxk[(L - 1) * D + d]), Wfp[D + d], s);
        logits[0] = s;
    } else if (tid == F + 1) {
        float s = 0.f;
        for (int d = 0; d < D; ++d) s = fmaf(hs[d], bfa[d], s);
        scal[0] = s;
    }
}

// ---- uks logits; one wave per neighbor row of hop 7 ----
__global__ void k_uks(const float* __restrict__ nb7, const float* __restrict__ v,
                      const float* __restrict__ scal, float* __restrict__ logits) {
    long n = (long)blockIdx.x * 4 + (threadIdx.x >> 6);
    int lane = threadIdx.x & 63;
    const float* row = nb7 + n * F;
    float s = 0.f;
    for (int f = lane; f < F; f += 64) s = fmaf(v[f], row[f], s);
    for (int off = 1; off < 64; off <<= 1) s += __shfl_xor(s, off, 64);
    if (lane == 0) logits[1 + n] = s + scal[0];
}

// ---- softmax over 32769 ----
__global__ void k_sm1(const float* __restrict__ logits, float* __restrict__ pm,
                      float* __restrict__ ps) {
    int bid = blockIdx.x, tid = threadIdx.x;
    int start = bid * 513;
    int stop = min(start + 513, N + 1);
    float m = -3.4e38f, s = 0.f;
    for (int i = start + tid; i < stop; i += 256) {
        float x = logits[i];
        if (x > m) { s = s * __expf(m - x) + 1.0f; m = x; }
        else       { s += __expf(x - m); }
    }
    for (int off = 1; off < 64; off <<= 1) {
        float m2 = __shfl_xor(m, off, 64);
        float s2 = __shfl_xor(s, off, 64);
        float M = fmaxf(m, m2);
        s = s * __expf(m - M) + s2 * __expf(m2 - M);
        m = M;
    }
    __shared__ float sm[4], ss[4];
    int lane = tid & 63, wid = tid >> 6;
    if (lane == 0) { sm[wid] = m; ss[wid] = s; }
    __syncthreads();
    if (tid == 0) {
        float M = fmaxf(fmaxf(sm[0], sm[1]), fmaxf(sm[2], sm[3]));
        float S = ss[0] * __expf(sm[0] - M) + ss[1] * __expf(sm[1] - M) +
                  ss[2] * __expf(sm[2] - M) + ss[3] * __expf(sm[3] - M);
        pm[bid] = M; ps[bid] = S;
    }
}

__global__ void k_sm2(const float* __restrict__ pm, const float* __restrict__ ps,
                      float* __restrict__ scal) {
    int lane = threadIdx.x;
    float m = pm[lane], s = ps[lane];
    for (int off = 1; off < 64; off <<= 1) {
        float m2 = __shfl_xor(m, off, 64);
        float s2 = __shfl_xor(s, off, 64);
        float M = fmaxf(m, m2);
        s = s * __expf(m - M) + s2 * __expf(m2 - M);
        m = M;
    }
    if (lane == 0) { scal[1] = m; scal[2] = s; }
}

__global__ void k_sm3(const float* __restrict__ logits, const float* __restrict__ scal,
                      float* __restrict__ out) {
    int i = blockIdx.x * 256 + threadIdx.x;
    if (i <= N) out[i] = __expf(logits[i] - scal[1]) / scal[2];
}

extern "C" void kernel_launch(void* const* d_in, const int* in_sizes, int n_in,
                              void* d_out, int out_size, void* d_ws, size_t ws_size,
                              hipStream_t stream) {
    const float* query = (const float*)d_in[0];
    const float* pn    = (const float*)d_in[1];
    const float* nb    = (const float*)d_in[2];
    const int*   aid   = (const int*)d_in[3];
    const float* Wih   = (const float*)d_in[4];
    const float* Whh   = (const float*)d_in[5];
    const float* bih   = (const float*)d_in[6];
    const float* bhh   = (const float*)d_in[7];
    const float* Wfa   = (const float*)d_in[8];
    const float* bfa   = (const float*)d_in[9];
    const float* Wfs   = (const float*)d_in[10];
    const float* bfs   = (const float*)d_in[11];
    const float* Wfp   = (const float*)d_in[12];
    const float* bfp   = (const float*)d_in[13];

    float* ws = (float*)d_ws;
    unsigned short* whi   = (unsigned short*)(ws + WS_WHI);
    unsigned short* wlo   = (unsigned short*)(ws + WS_WLO);
    unsigned*       hmaxk = (unsigned*)(ws + WS_HMAXK);
    float* hsel   = ws + WS_HSEL;
    float* gi     = ws + WS_GI;
    float* hbuf   = ws + WS_HBUF;
    float* v      = ws + WS_V;
    float* scal   = ws + WS_SCAL;
    float* pm     = ws + WS_PM;
    float* psum   = ws + WS_PS;
    float* logits = ws + WS_LOGITS;
    float* out    = (float*)d_out;

    k_wbf <<<(128 * FP2 + 255) / 256, 256, 0, stream>>>(Wfa, whi, wlo);
    k_init<<<(L * D + 255) / 256, 256, 0, stream>>>(hmaxk);
    k_big <<<L * 256, 256, 0, stream>>>(nb, whi, wlo, bfa, aid, hmaxk, hsel);
    k_gi  <<<(L * 3 * H + 255) / 256, 256, 0, stream>>>(Wih, bih, pn, hmaxk, hsel, gi);

    for (int t = 0; t < L; ++t) {
        const float* hin = (t == 0) ? query : (hbuf + ((t - 1) & 1) * H);
        float* hout = hbuf + (t & 1) * H;
        k_step<<<(H + 3) / 4, 256, 0, stream>>>(Whh, bhh, gi + t * 3 * H, hin, hout);
    }
    const float* qt = hbuf + ((L - 1) & 1) * H;

    k_final<<<1, 576, 0, stream>>>(qt, Wfs, bfs, Wfa, bfa, Wfp, bfp, hmaxk, v, scal, logits);
    k_uks  <<<N / 4, 256, 0, stream>>>(nb + (long)(L - 1) * N * F, v, scal, logits);

    k_sm1<<<64, 256, 0, stream>>>(logits, pm, psum);
    k_sm2<<<1, 64, 0, stream>>>(pm, psum, scal);
    k_sm3<<<(N + 1 + 255) / 256, 256, 0, stream>>>(logits, scal, out);
}

// Round 4
// 339.515 us; speedup vs baseline: 7.4032x; 1.3459x over previous
//
#include <hip/hip_runtime.h>
#include <math.h>

#define L 8
#define N 32768
#define H 404
#define D 128
#define F 532
#define FP2 576           // F padded to 9*64 for BK=64 tiling (zeros beyond 532)
#define KT 9              // K-tiles of 64

typedef __attribute__((ext_vector_type(8))) _Float16 half8;
typedef __attribute__((ext_vector_type(4))) float f32x4;

// workspace layout (float offsets)
#define WS_WH      0                        // 128*576 fp16 = 36864 floats
#define WS_HMAXK   (WS_WH + 128*FP2/2)      // 8*128 uint keys
#define WS_HSEL    (WS_HMAXK + L * D)       // 7*128
#define WS_GI      (WS_HSEL + (L - 1) * D)  // 8*1212
#define WS_HBUF    (WS_GI + L * 3 * H)      // 2*404
#define WS_V       (WS_HBUF + 2 * H)        // 532
#define WS_SCAL    (WS_V + F)               // c, M, S, spare
#define WS_PM      (WS_SCAL + 4)            // 64
#define WS_PS      (WS_PM + 64)             // 64
#define WS_LOGITS  (WS_PS + 64)             // 32769

__device__ __forceinline__ unsigned encf(float f) {
    unsigned u = __float_as_uint(f);
    return (u & 0x80000000u) ? ~u : (u | 0x80000000u);
}
__device__ __forceinline__ float decf(unsigned u) {
    unsigned b = (u & 0x80000000u) ? (u ^ 0x80000000u) : ~u;
    return __uint_as_float(b);
}
__device__ __forceinline__ float sigmoidf_(float x) {
    return 1.0f / (1.0f + __expf(-x));
}
__device__ __forceinline__ unsigned pk_f16(float a, float b) {
    auto h = __builtin_amdgcn_cvt_pkrtz(a, b);   // __fp16 ext_vector(2)
    return *(unsigned*)&h;
}

// ---- prep: W_fa (D x F) -> fp16 [d][FP2] zero-padded; init hmax keys ----
__global__ void k_prep(const float* __restrict__ Wfa, unsigned short* __restrict__ wh,
                       unsigned* __restrict__ keys) {
    int i = blockIdx.x * 256 + threadIdx.x;
    if (i < L * D) keys[i] = 0u;           // decodes to -NaN, below all finite
    if (i >= 128 * FP2) return;
    int d = i / FP2, f = i % FP2;
    float v = (f < F) ? Wfa[d * F + f] : 0.0f;
    _Float16 h = (_Float16)v;
    wh[i] = *(unsigned short*)&h;
}

// ---- big einsum via single fp16 MFMA + column max + selected-row extraction ----
// grid 2048: l = bid>>8, 128-row chunk = bid&255. 4 waves, each 64x64 output.
__global__ __launch_bounds__(256, 4)
void k_big(const float* __restrict__ nb, const unsigned short* __restrict__ wh,
           const float* __restrict__ bfa, const int* __restrict__ aid,
           unsigned* __restrict__ hmaxk, float* __restrict__ hsel) {
    __shared__ _Float16 As[128 * 64];      // 16 KB, row = 128 B
    __shared__ _Float16 Bs[128 * 64];      // 16 KB

    const int bid = blockIdx.x;
    const int l_hop = bid >> 8;
    const int row0 = (bid & 255) * 128;
    const int tid = threadIdx.x;
    const int lane = tid & 63, w = tid >> 6;
    const int wm = w >> 1, wn = w & 1;
    const int lr = lane & 15, kg = lane >> 4;

    const float* xbase = nb + ((long)l_hop * N + row0) * F;

    const int swz = (lr & 7) << 4;
    int abase[4], bbase[4];
#pragma unroll
    for (int m = 0; m < 4; ++m)
        abase[m] = (wm * 64 + m * 16 + lr) * 128 + ((kg * 16) ^ swz);
#pragma unroll
    for (int n = 0; n < 4; ++n)
        bbase[n] = (wn * 64 + n * 16 + lr) * 128 + ((kg * 16) ^ swz);

    // acc init = bias (broadcast down each output column d)
    f32x4 acc[4][4];
    float bv[4];
#pragma unroll
    for (int n = 0; n < 4; ++n) bv[n] = bfa[wn * 64 + n * 16 + lr];
#pragma unroll
    for (int m = 0; m < 4; ++m)
#pragma unroll
        for (int n = 0; n < 4; ++n) {
            acc[m][n][0] = bv[n]; acc[m][n][1] = bv[n];
            acc[m][n][2] = bv[n]; acc[m][n][3] = bv[n];
        }

    const int ar = tid >> 4, ac4 = tid & 15;   // A-stage: row base, float4 idx
    const int bd = tid >> 3, bc16 = tid & 7;   // B-stage

    for (int kt = 0; kt < KT; ++kt) {
        const int fc = kt * 64;
        __syncthreads();
        // stage A: 128 rows x 64 f fp32 -> fp16 (cvt_pkrtz), swizzled 8B stores
#pragma unroll
        for (int it = 0; it < 8; ++it) {
            int r = ar + it * 16;
            int fg = fc + ac4 * 4;
            float4 x = make_float4(0.f, 0.f, 0.f, 0.f);
            if (fg < F) x = *(const float4*)(xbase + (long)r * F + fg);
            uint2 u = { pk_f16(x.x, x.y), pk_f16(x.z, x.w) };
            int wb = r * 128 + ((ac4 * 8) ^ ((r & 7) << 4));
            *(uint2*)((char*)As + wb) = u;
        }
        // stage B: 128 d x 64 k fp16 (pre-converted), 16B copies
#pragma unroll
        for (int it = 0; it < 4; ++it) {
            int dd = bd + it * 32;
            long so = (long)dd * FP2 + fc + bc16 * 8;
            int wb = dd * 128 + ((bc16 * 16) ^ ((dd & 7) << 4));
            *(half8*)((char*)Bs + wb) = *(const half8*)(wh + so);
        }
        __syncthreads();

#pragma unroll
        for (int ks = 0; ks < 2; ++ks) {
            const int kx = ks << 6;
            half8 a[4], b[4];
#pragma unroll
            for (int m = 0; m < 4; ++m)
                a[m] = *(const half8*)((char*)As + (abase[m] ^ kx));
#pragma unroll
            for (int n = 0; n < 4; ++n)
                b[n] = *(const half8*)((char*)Bs + (bbase[n] ^ kx));
#pragma unroll
            for (int m = 0; m < 4; ++m)
#pragma unroll
                for (int n = 0; n < 4; ++n)
                    acc[m][n] = __builtin_amdgcn_mfma_f32_16x16x32_f16(a[m], b[n], acc[m][n], 0, 0, 0);
        }
    }

    __syncthreads();   // LDS reads done; reuse As for cross-wave max

    // selected-action row (compile-time acc indexing)
    if (l_hop < L - 1) {
        int arow = aid[l_hop];
        int br = arow - row0;
        if (br >= 0 && br < 128 && (br >> 6) == wm && ((br >> 2) & 3) == kg) {
            int msel = (br >> 4) & 3, rsel = br & 3;
#pragma unroll
            for (int n = 0; n < 4; ++n) {
                float vsel = 0.f;
#pragma unroll
                for (int m = 0; m < 4; ++m)
#pragma unroll
                    for (int r = 0; r < 4; ++r)
                        if (m == msel && r == rsel) vsel = acc[m][n][r];
                hsel[l_hop * D + wn * 64 + n * 16 + lr] = vsel;
            }
        }
    }

    // column max: thread-local -> cross-lane-group shfl -> cross-wave LDS -> atomic
    float cmax[4];
#pragma unroll
    for (int n = 0; n < 4; ++n) {
        float m0 = acc[0][n][0];
#pragma unroll
        for (int m = 0; m < 4; ++m)
#pragma unroll
            for (int r = 0; r < 4; ++r) m0 = fmaxf(m0, acc[m][n][r]);
        m0 = fmaxf(m0, __shfl_xor(m0, 16, 64));
        m0 = fmaxf(m0, __shfl_xor(m0, 32, 64));
        cmax[n] = m0;
    }
    float* wmaxp = (float*)As;   // [2][128]
    if (kg == 0) {
#pragma unroll
        for (int n = 0; n < 4; ++n)
            wmaxp[wm * 128 + wn * 64 + n * 16 + lr] = cmax[n];
    }
    __syncthreads();
    if (tid < 128) {
        float mval = fmaxf(wmaxp[tid], wmaxp[128 + tid]);
        atomicMax(&hmaxk[l_hop * D + tid], encf(mval));
    }
}

// ---- precompute gi for all 8 GRU steps ----
__global__ void k_gi(const float* __restrict__ Wih, const float* __restrict__ bih,
                     const float* __restrict__ pn, const unsigned* __restrict__ hmaxk,
                     const float* __restrict__ hsel, float* __restrict__ gi) {
    int i = blockIdx.x * 256 + threadIdx.x;
    if (i >= L * 3 * H) return;
    int t = i / (3 * H), row = i % (3 * H);
    float s = bih[row];
    const float* wr = Wih + (long)row * 3 * D;
    for (int k = 0; k < 3 * D; ++k) {
        float x;
        if (t == 0) {
            x = (k < 2 * D) ? 0.0f : pn[k - 2 * D];
        } else {
            if (k < D)            x = decf(hmaxk[(t - 1) * D + k]);
            else if (k < 2 * D)   x = hsel[(t - 1) * D + (k - D)];
            else                  x = pn[t * D + (k - 2 * D)];
        }
        s = fmaf(x, wr[k], s);
    }
    gi[i] = s;
}

// ---- one GRU step; one wave per hidden index ----
__global__ void k_step(const float* __restrict__ Whh, const float* __restrict__ bhh,
                       const float* __restrict__ gi_t, const float* __restrict__ hin,
                       float* __restrict__ hout) {
    int wave = blockIdx.x * 4 + (threadIdx.x >> 6);
    int lane = threadIdx.x & 63;
    if (wave >= H) return;
    int j = wave;
    float pr = 0.f, pz = 0.f, pnn = 0.f;
    for (int i = lane; i < H; i += 64) {
        float hv = hin[i];
        pr  = fmaf(Whh[(long)j * H + i], hv, pr);
        pz  = fmaf(Whh[(long)(H + j) * H + i], hv, pz);
        pnn = fmaf(Whh[(long)(2 * H + j) * H + i], hv, pnn);
    }
    for (int off = 1; off < 64; off <<= 1) {
        pr  += __shfl_xor(pr, off, 64);
        pz  += __shfl_xor(pz, off, 64);
        pnn += __shfl_xor(pnn, off, 64);
    }
    if (lane == 0) {
        float r = sigmoidf_(gi_t[j] + pr + bhh[j]);
        float z = sigmoidf_(gi_t[H + j] + pz + bhh[H + j]);
        float nn = tanhf(gi_t[2 * H + j] + r * (pnn + bhh[2 * H + j]));
        hout[j] = (1.0f - z) * nn + z * hin[j];
    }
}

// ---- hSt, u0, v = W_fa^T hSt, c = hSt.b_fa ----
__global__ void k_final(const float* __restrict__ qt, const float* __restrict__ Wfs,
                        const float* __restrict__ bfs, const float* __restrict__ Wfa,
                        const float* __restrict__ bfa, const float* __restrict__ Wfp,
                        const float* __restrict__ bfp, const unsigned* __restrict__ hmaxk,
                        float* __restrict__ v, float* __restrict__ scal,
                        float* __restrict__ logits) {
    __shared__ float hs[D];
    int tid = threadIdx.x;
    if (tid < D) {
        float s = bfs[tid];
        for (int j = 0; j < H; ++j) s = fmaf(qt[j], Wfs[tid * H + j], s);
        hs[tid] = s;
    }
    __syncthreads();
    if (tid < F) {
        float s = 0.f;
        for (int d = 0; d < D; ++d) s = fmaf(hs[d], Wfa[d * F + tid], s);
        v[tid] = s;
    } else if (tid == F) {
        float s = bfp[0];
        for (int d = 0; d < D; ++d) s = fmaf(hs[d], Wfp[d], s);
        for (int d = 0; d < D; ++d) s = fmaf(decf(hmaxk[(L - 1) * D + d]), Wfp[D + d], s);
        logits[0] = s;
    } else if (tid == F + 1) {
        float s = 0.f;
        for (int d = 0; d < D; ++d) s = fmaf(hs[d], bfa[d], s);
        scal[0] = s;
    }
}

// ---- uks logits (exact fp32 path); one wave per neighbor row of hop 7 ----
__global__ void k_uks(const float* __restrict__ nb7, const float* __restrict__ v,
                      const float* __restrict__ scal, float* __restrict__ logits) {
    long n = (long)blockIdx.x * 4 + (threadIdx.x >> 6);
    int lane = threadIdx.x & 63;
    const float* row = nb7 + n * F;
    float s = 0.f;
    for (int f = lane; f < F; f += 64) s = fmaf(v[f], row[f], s);
    for (int off = 1; off < 64; off <<= 1) s += __shfl_xor(s, off, 64);
    if (lane == 0) logits[1 + n] = s + scal[0];
}

// ---- softmax over 32769 ----
__global__ void k_sm1(const float* __restrict__ logits, float* __restrict__ pm,
                      float* __restrict__ ps) {
    int bid = blockIdx.x, tid = threadIdx.x;
    int start = bid * 513;
    int stop = min(start + 513, N + 1);
    float m = -3.4e38f, s = 0.f;
    for (int i = start + tid; i < stop; i += 256) {
        float x = logits[i];
        if (x > m) { s = s * __expf(m - x) + 1.0f; m = x; }
        else       { s += __expf(x - m); }
    }
    for (int off = 1; off < 64; off <<= 1) {
        float m2 = __shfl_xor(m, off, 64);
        float s2 = __shfl_xor(s, off, 64);
        float M = fmaxf(m, m2);
        s = s * __expf(m - M) + s2 * __expf(m2 - M);
        m = M;
    }
    __shared__ float sm[4], ss[4];
    int lane = tid & 63, wid = tid >> 6;
    if (lane == 0) { sm[wid] = m; ss[wid] = s; }
    __syncthreads();
    if (tid == 0) {
        float M = fmaxf(fmaxf(sm[0], sm[1]), fmaxf(sm[2], sm[3]));
        float S = ss[0] * __expf(sm[0] - M) + ss[1] * __expf(sm[1] - M) +
                  ss[2] * __expf(sm[2] - M) + ss[3] * __expf(sm[3] - M);
        pm[bid] = M; ps[bid] = S;
    }
}

__global__ void k_sm2(const float* __restrict__ pm, const float* __restrict__ ps,
                      float* __restrict__ scal) {
    int lane = threadIdx.x;
    float m = pm[lane], s = ps[lane];
    for (int off = 1; off < 64; off <<= 1) {
        float m2 = __shfl_xor(m, off, 64);
        float s2 = __shfl_xor(s, off, 64);
        float M = fmaxf(m, m2);
        s = s * __expf(m - M) + s2 * __expf(m2 - M);
        m = M;
    }
    if (lane == 0) { scal[1] = m; scal[2] = s; }
}

__global__ void k_sm3(const float* __restrict__ logits, const float* __restrict__ scal,
                      float* __restrict__ out) {
    int i = blockIdx.x * 256 + threadIdx.x;
    if (i <= N) out[i] = __expf(logits[i] - scal[1]) / scal[2];
}

extern "C" void kernel_launch(void* const* d_in, const int* in_sizes, int n_in,
                              void* d_out, int out_size, void* d_ws, size_t ws_size,
                              hipStream_t stream) {
    const float* query = (const float*)d_in[0];
    const float* pn    = (const float*)d_in[1];
    const float* nb    = (const float*)d_in[2];
    const int*   aid   = (const int*)d_in[3];
    const float* Wih   = (const float*)d_in[4];
    const float* Whh   = (const float*)d_in[5];
    const float* bih   = (const float*)d_in[6];
    const float* bhh   = (const float*)d_in[7];
    const float* Wfa   = (const float*)d_in[8];
    const float* bfa   = (const float*)d_in[9];
    const float* Wfs   = (const float*)d_in[10];
    const float* bfs   = (const float*)d_in[11];
    const float* Wfp   = (const float*)d_in[12];
    const float* bfp   = (const float*)d_in[13];

    float* ws = (float*)d_ws;
    unsigned short* wh    = (unsigned short*)(ws + WS_WH);
    unsigned*       hmaxk = (unsigned*)(ws + WS_HMAXK);
    float* hsel   = ws + WS_HSEL;
    float* gi     = ws + WS_GI;
    float* hbuf   = ws + WS_HBUF;
    float* v      = ws + WS_V;
    float* scal   = ws + WS_SCAL;
    float* pm     = ws + WS_PM;
    float* psum   = ws + WS_PS;
    float* logits = ws + WS_LOGITS;
    float* out    = (float*)d_out;

    k_prep<<<(128 * FP2 + 255) / 256, 256, 0, stream>>>(Wfa, wh, hmaxk);
    k_big <<<L * 256, 256, 0, stream>>>(nb, wh, bfa, aid, hmaxk, hsel);
    k_gi  <<<(L * 3 * H + 255) / 256, 256, 0, stream>>>(Wih, bih, pn, hmaxk, hsel, gi);

    for (int t = 0; t < L; ++t) {
        const float* hin = (t == 0) ? query : (hbuf + ((t - 1) & 1) * H);
        float* hout = hbuf + (t & 1) * H;
        k_step<<<(H + 3) / 4, 256, 0, stream>>>(Whh, bhh, gi + t * 3 * H, hin, hout);
    }
    const float* qt = hbuf + ((L - 1) & 1) * H;

    k_final<<<1, 576, 0, stream>>>(qt, Wfs, bfs, Wfa, bfa, Wfp, bfp, hmaxk, v, scal, logits);
    k_uks  <<<N / 4, 256, 0, stream>>>(nb + (long)(L - 1) * N * F, v, scal, logits);

    k_sm1<<<64, 256, 0, stream>>>(logits, pm, psum);
    k_sm2<<<1, 64, 0, stream>>>(pm, psum, scal);
    k_sm3<<<(N + 1 + 255) / 256, 256, 0, stream>>>(logits, scal, out);
}

// Round 5
// 338.467 us; speedup vs baseline: 7.4261x; 1.0031x over previous
//
#include <hip/hip_runtime.h>
#include <math.h>

#define L 8
#define N 32768
#define H 404
#define D 128
#define F 532
#define FP2 576           // F padded to 9*64 for BK=64 tiling (zeros beyond 532)
#define KT 9              // K-tiles of 64
#define GRU_BLOCKS 101    // (H+3)/4 : one wave per hidden index

typedef __attribute__((ext_vector_type(8))) _Float16 half8;
typedef __attribute__((ext_vector_type(4))) float f32x4;

// workspace layout (float offsets)
#define WS_WH      0                        // 128*576 fp16 = 36864 floats
#define WS_HMAXK   (WS_WH + 128*FP2/2)      // 8*128 uint keys
#define WS_HSEL    (WS_HMAXK + L * D)       // 7*128
#define WS_GI      (WS_HSEL + (L - 1) * D)  // 8*1212
#define WS_HBUF    (WS_GI + L * 3 * H)      // 2*404
#define WS_V       (WS_HBUF + 2 * H)        // 532
#define WS_HS      (WS_V + F)               // 128
#define WS_SCAL    (WS_HS + D)              // c, M, S, spare
#define WS_CNT     (WS_SCAL + 4)            // barrier counter (1 uint)
#define WS_LOGITS  (WS_CNT + 4)             // 32769

__device__ __forceinline__ unsigned encf(float f) {
    unsigned u = __float_as_uint(f);
    return (u & 0x80000000u) ? ~u : (u | 0x80000000u);
}
__device__ __forceinline__ float decf(unsigned u) {
    unsigned b = (u & 0x80000000u) ? (u ^ 0x80000000u) : ~u;
    return __uint_as_float(b);
}
__device__ __forceinline__ float sigmoidf_(float x) {
    return 1.0f / (1.0f + __expf(-x));
}
__device__ __forceinline__ unsigned pk_f16(float a, float b) {
    auto h = __builtin_amdgcn_cvt_pkrtz(a, b);   // __fp16 ext_vector(2)
    return *(unsigned*)&h;
}

// ---- prep: W_fa -> fp16 [d][FP2]; init hmax keys; zero barrier counter ----
__global__ void k_prep(const float* __restrict__ Wfa, unsigned short* __restrict__ wh,
                       unsigned* __restrict__ keys, unsigned* __restrict__ cnt) {
    int i = blockIdx.x * 256 + threadIdx.x;
    if (i == 0) *cnt = 0u;
    if (i < L * D) keys[i] = 0u;           // decodes below all finite values
    if (i >= 128 * FP2) return;
    int d = i / FP2, f = i % FP2;
    float v = (f < F) ? Wfa[d * F + f] : 0.0f;
    _Float16 h = (_Float16)v;
    wh[i] = *(unsigned short*)&h;
}

// ---- big einsum: fp16 MFMA, T14 register-prefetch of next A tile ----
// grid 2048: l = bid>>8, 128-row chunk = bid&255. 4 waves, each 64x64 output.
__global__ __launch_bounds__(256, 3)
void k_big(const float* __restrict__ nb, const unsigned short* __restrict__ wh,
           const float* __restrict__ bfa, const int* __restrict__ aid,
           unsigned* __restrict__ hmaxk, float* __restrict__ hsel) {
    __shared__ _Float16 As[128 * 64];      // 16 KB, row = 128 B
    __shared__ _Float16 Bs[128 * 64];      // 16 KB

    const int bid = blockIdx.x;
    const int l_hop = bid >> 8;
    const int row0 = (bid & 255) * 128;
    const int tid = threadIdx.x;
    const int lane = tid & 63, w = tid >> 6;
    const int wm = w >> 1, wn = w & 1;
    const int lr = lane & 15, kg = lane >> 4;

    const float* xbase = nb + ((long)l_hop * N + row0) * F;

    const int swz = (lr & 7) << 4;
    int abase[4], bbase[4];
#pragma unroll
    for (int m = 0; m < 4; ++m)
        abase[m] = (wm * 64 + m * 16 + lr) * 128 + ((kg * 16) ^ swz);
#pragma unroll
    for (int n = 0; n < 4; ++n)
        bbase[n] = (wn * 64 + n * 16 + lr) * 128 + ((kg * 16) ^ swz);

    // acc init = bias (broadcast down each output column d)
    f32x4 acc[4][4];
    float bv[4];
#pragma unroll
    for (int n = 0; n < 4; ++n) bv[n] = bfa[wn * 64 + n * 16 + lr];
#pragma unroll
    for (int m = 0; m < 4; ++m)
#pragma unroll
        for (int n = 0; n < 4; ++n) {
            acc[m][n][0] = bv[n]; acc[m][n][1] = bv[n];
            acc[m][n][2] = bv[n]; acc[m][n][3] = bv[n];
        }

    const int ar = tid >> 4, ac4 = tid & 15;   // A-stage: row base, float4 idx
    const int bd = tid >> 3, bc16 = tid & 7;   // B-stage

    // prologue: prefetch tile 0 into registers (fc=0 -> always in range)
    float4 pa[8];
#pragma unroll
    for (int it = 0; it < 8; ++it) {
        int r = ar + it * 16;
        pa[it] = *(const float4*)(xbase + (long)r * F + ac4 * 4);
    }

    for (int kt = 0; kt < KT; ++kt) {
        const int fc = kt * 64;
        __syncthreads();                       // LDS free (prev MFMA done)
        // store prefetched A regs -> LDS (fp32 -> fp16 cvt), swizzled
#pragma unroll
        for (int it = 0; it < 8; ++it) {
            int r = ar + it * 16;
            float4 x = pa[it];
            uint2 u = { pk_f16(x.x, x.y), pk_f16(x.z, x.w) };
            int wb = r * 128 + ((ac4 * 8) ^ ((r & 7) << 4));
            *(uint2*)((char*)As + wb) = u;
        }
        // B tile (L2-hot): load + store
#pragma unroll
        for (int it = 0; it < 4; ++it) {
            int dd = bd + it * 32;
            long so = (long)dd * FP2 + fc + bc16 * 8;
            int wb = dd * 128 + ((bc16 * 16) ^ ((dd & 7) << 4));
            *(half8*)((char*)Bs + wb) = *(const half8*)(wh + so);
        }
        // prefetch NEXT A tile: loads in flight across barrier + MFMA phase
        if (kt + 1 < KT) {
            const int fc2 = fc + 64;
#pragma unroll
            for (int it = 0; it < 8; ++it) {
                int r = ar + it * 16;
                int fg = fc2 + ac4 * 4;
                float4 x = make_float4(0.f, 0.f, 0.f, 0.f);
                if (fg < F) x = *(const float4*)(xbase + (long)r * F + fg);
                pa[it] = x;
            }
        }
        __syncthreads();                       // LDS ready

#pragma unroll
        for (int ks = 0; ks < 2; ++ks) {
            const int kx = ks << 6;
            half8 a[4], b[4];
#pragma unroll
            for (int m = 0; m < 4; ++m)
                a[m] = *(const half8*)((char*)As + (abase[m] ^ kx));
#pragma unroll
            for (int n = 0; n < 4; ++n)
                b[n] = *(const half8*)((char*)Bs + (bbase[n] ^ kx));
#pragma unroll
            for (int m = 0; m < 4; ++m)
#pragma unroll
                for (int n = 0; n < 4; ++n)
                    acc[m][n] = __builtin_amdgcn_mfma_f32_16x16x32_f16(a[m], b[n], acc[m][n], 0, 0, 0);
        }
    }

    __syncthreads();   // LDS reads done; reuse As for cross-wave max

    // selected-action row (compile-time acc indexing)
    if (l_hop < L - 1) {
        int arow = aid[l_hop];
        int br = arow - row0;
        if (br >= 0 && br < 128 && (br >> 6) == wm && ((br >> 2) & 3) == kg) {
            int msel = (br >> 4) & 3, rsel = br & 3;
#pragma unroll
            for (int n = 0; n < 4; ++n) {
                float vsel = 0.f;
#pragma unroll
                for (int m = 0; m < 4; ++m)
#pragma unroll
                    for (int r = 0; r < 4; ++r)
                        if (m == msel && r == rsel) vsel = acc[m][n][r];
                hsel[l_hop * D + wn * 64 + n * 16 + lr] = vsel;
            }
        }
    }

    // column max: thread-local -> cross-lane-group shfl -> cross-wave LDS -> atomic
    float cmax[4];
#pragma unroll
    for (int n = 0; n < 4; ++n) {
        float m0 = acc[0][n][0];
#pragma unroll
        for (int m = 0; m < 4; ++m)
#pragma unroll
            for (int r = 0; r < 4; ++r) m0 = fmaxf(m0, acc[m][n][r]);
        m0 = fmaxf(m0, __shfl_xor(m0, 16, 64));
        m0 = fmaxf(m0, __shfl_xor(m0, 32, 64));
        cmax[n] = m0;
    }
    float* wmaxp = (float*)As;   // [2][128]
    if (kg == 0) {
#pragma unroll
        for (int n = 0; n < 4; ++n)
            wmaxp[wm * 128 + wn * 64 + n * 16 + lr] = cmax[n];
    }
    __syncthreads();
    if (tid < 128) {
        float mval = fmaxf(wmaxp[tid], wmaxp[128 + tid]);
        atomicMax(&hmaxk[l_hop * D + tid], encf(mval));
    }
}

// ---- precompute gi for all 8 GRU steps ----
__global__ void k_gi(const float* __restrict__ Wih, const float* __restrict__ bih,
                     const float* __restrict__ pn, const unsigned* __restrict__ hmaxk,
                     const float* __restrict__ hsel, float* __restrict__ gi) {
    int i = blockIdx.x * 256 + threadIdx.x;
    if (i >= L * 3 * H) return;
    int t = i / (3 * H), row = i % (3 * H);
    float s = bih[row];
    const float* wr = Wih + (long)row * 3 * D;
    for (int k = 0; k < 3 * D; ++k) {
        float x;
        if (t == 0) {
            x = (k < 2 * D) ? 0.0f : pn[k - 2 * D];
        } else {
            if (k < D)            x = decf(hmaxk[(t - 1) * D + k]);
            else if (k < 2 * D)   x = hsel[(t - 1) * D + (k - D)];
            else                  x = pn[t * D + (k - 2 * D)];
        }
        s = fmaf(x, wr[k], s);
    }
    gi[i] = s;
}

// ---- all 8 GRU steps in ONE kernel; one wave per hidden j; grid barrier ----
// 101 blocks of 256 threads: co-resident on 256 CUs. Whh rows cached in regs.
__global__ __launch_bounds__(256, 1)
void k_gru(const float* __restrict__ Whh, const float* __restrict__ bhh,
           const float* __restrict__ gi, const float* __restrict__ query,
           float* __restrict__ hbuf, unsigned* __restrict__ cnt) {
    const int tid = threadIdx.x;
    const int lane = tid & 63;
    const int j = blockIdx.x * 4 + (tid >> 6);     // 0..403 exactly

    // cache the 3 Whh rows for this j across all 8 steps
    float wr[7], wz[7], wnn[7];
#pragma unroll
    for (int c = 0; c < 7; ++c) {
        int i = lane + c * 64;
        bool ok = i < H;
        wr[c]  = ok ? Whh[(long)j * H + i]           : 0.f;
        wz[c]  = ok ? Whh[(long)(H + j) * H + i]     : 0.f;
        wnn[c] = ok ? Whh[(long)(2 * H + j) * H + i] : 0.f;
    }
    float b_r = 0.f, b_z = 0.f, b_n = 0.f;
    if (lane == 0) { b_r = bhh[j]; b_z = bhh[H + j]; b_n = bhh[2 * H + j]; }

    for (int t = 0; t < L; ++t) {
        const float* hin = (t == 0) ? query : (hbuf + ((t - 1) & 1) * H);
        float* hout = hbuf + (t & 1) * H;
        float pr = 0.f, pz = 0.f, pn2 = 0.f;
#pragma unroll
        for (int c = 0; c < 7; ++c) {
            int i = lane + c * 64;
            float hv = 0.f;
            if (i < H)
                hv = (t == 0) ? hin[i]
                              : __hip_atomic_load(hin + i, __ATOMIC_RELAXED,
                                                  __HIP_MEMORY_SCOPE_AGENT);
            pr  = fmaf(wr[c],  hv, pr);
            pz  = fmaf(wz[c],  hv, pz);
            pn2 = fmaf(wnn[c], hv, pn2);
        }
        for (int off = 1; off < 64; off <<= 1) {
            pr  += __shfl_xor(pr, off, 64);
            pz  += __shfl_xor(pz, off, 64);
            pn2 += __shfl_xor(pn2, off, 64);
        }
        if (lane == 0) {
            const float* gt = gi + t * 3 * H;
            float hprev = (t == 0) ? hin[j]
                                   : __hip_atomic_load(hin + j, __ATOMIC_RELAXED,
                                                       __HIP_MEMORY_SCOPE_AGENT);
            float r  = sigmoidf_(gt[j] + pr + b_r);
            float z  = sigmoidf_(gt[H + j] + pz + b_z);
            float nn = tanhf(gt[2 * H + j] + r * (pn2 + b_n));
            float hv = (1.0f - z) * nn + z * hprev;
            __hip_atomic_store(hout + j, hv, __ATOMIC_RELAXED,
                               __HIP_MEMORY_SCOPE_AGENT);
        }
        if (t < L - 1) {   // grid barrier between steps (last step: kernel-end)
            __syncthreads();
            if (tid == 0) {
                __hip_atomic_fetch_add(cnt, 1u, __ATOMIC_RELEASE,
                                       __HIP_MEMORY_SCOPE_AGENT);
                unsigned target = (unsigned)GRU_BLOCKS * (t + 1);
                while (__hip_atomic_load(cnt, __ATOMIC_ACQUIRE,
                                         __HIP_MEMORY_SCOPE_AGENT) < target) {}
            }
            __syncthreads();
        }
    }
}

// ---- hSt (coalesced wave-reduce), u0, c ----
__global__ void k_final1(const float* __restrict__ qt, const float* __restrict__ Wfs,
                         const float* __restrict__ bfs, const float* __restrict__ Wfp,
                         const float* __restrict__ bfp, const float* __restrict__ bfa,
                         const unsigned* __restrict__ hmaxk, float* __restrict__ hs_out,
                         float* __restrict__ scal, float* __restrict__ logits) {
    __shared__ float hs[D];
    int tid = threadIdx.x, lane = tid & 63, wid = tid >> 6;   // 8 waves
    for (int dd = 0; dd < 16; ++dd) {
        int d = wid * 16 + dd;
        float s = 0.f;
#pragma unroll
        for (int c = 0; c < 7; ++c) {
            int i = lane + c * 64;
            if (i < H) s = fmaf(qt[i], Wfs[(long)d * H + i], s);
        }
        for (int off = 1; off < 64; off <<= 1) s += __shfl_xor(s, off, 64);
        if (lane == 0) hs[d] = s + bfs[d];
    }
    __syncthreads();
    if (tid == 0) {
        float s = bfp[0], c2 = 0.f;
        for (int d = 0; d < D; ++d) {
            s  = fmaf(hs[d], Wfp[d], s);
            s  = fmaf(decf(hmaxk[(L - 1) * D + d]), Wfp[D + d], s);
            c2 = fmaf(hs[d], bfa[d], c2);
        }
        logits[0] = s;
        scal[0] = c2;
    }
    if (tid < D) hs_out[tid] = hs[tid];
}

// ---- v = W_fa^T hSt (parallel over f) ----
__global__ void k_final2(const float* __restrict__ hs, const float* __restrict__ Wfa,
                         float* __restrict__ v) {
    int f = blockIdx.x * 128 + threadIdx.x;
    if (f >= F) return;
    float s = 0.f;
    for (int d = 0; d < D; ++d) s = fmaf(hs[d], Wfa[(long)d * F + f], s);
    v[f] = s;
}

// ---- uks logits (exact fp32 path); one wave per neighbor row of hop 7 ----
__global__ void k_uks(const float* __restrict__ nb7, const float* __restrict__ v,
                      const float* __restrict__ scal, float* __restrict__ logits) {
    long n = (long)blockIdx.x * 4 + (threadIdx.x >> 6);
    int lane = threadIdx.x & 63;
    const float* row = nb7 + n * F;
    float s = 0.f;
    for (int f = lane; f < F; f += 64) s = fmaf(v[f], row[f], s);
    for (int off = 1; off < 64; off <<= 1) s += __shfl_xor(s, off, 64);
    if (lane == 0) logits[1 + n] = s + scal[0];
}

// ---- softmax reduce over 32769 (single block, 1024 thr) ----
__global__ void k_sm12(const float* __restrict__ logits, float* __restrict__ scal) {
    __shared__ float sm[16], ss[16];
    int tid = threadIdx.x, lane = tid & 63, wid = tid >> 6;
    float m = -3.4e38f, s = 0.f;
    for (int i = tid; i <= N; i += 1024) {
        float x = logits[i];
        if (x > m) { s = s * __expf(m - x) + 1.0f; m = x; }
        else       { s += __expf(x - m); }
    }
    for (int off = 1; off < 64; off <<= 1) {
        float m2 = __shfl_xor(m, off, 64);
        float s2 = __shfl_xor(s, off, 64);
        float M = fmaxf(m, m2);
        s = s * __expf(m - M) + s2 * __expf(m2 - M);
        m = M;
    }
    if (lane == 0) { sm[wid] = m; ss[wid] = s; }
    __syncthreads();
    if (tid == 0) {
        float M = sm[0], S = 0.f;
        for (int k = 1; k < 16; ++k) M = fmaxf(M, sm[k]);
        for (int k = 0; k < 16; ++k) S += ss[k] * __expf(sm[k] - M);
        scal[1] = M; scal[2] = S;
    }
}

__global__ void k_sm3(const float* __restrict__ logits, const float* __restrict__ scal,
                      float* __restrict__ out) {
    int i = blockIdx.x * 256 + threadIdx.x;
    if (i <= N) out[i] = __expf(logits[i] - scal[1]) / scal[2];
}

extern "C" void kernel_launch(void* const* d_in, const int* in_sizes, int n_in,
                              void* d_out, int out_size, void* d_ws, size_t ws_size,
                              hipStream_t stream) {
    const float* query = (const float*)d_in[0];
    const float* pn    = (const float*)d_in[1];
    const float* nb    = (const float*)d_in[2];
    const int*   aid   = (const int*)d_in[3];
    const float* Wih   = (const float*)d_in[4];
    const float* Whh   = (const float*)d_in[5];
    const float* bih   = (const float*)d_in[6];
    const float* bhh   = (const float*)d_in[7];
    const float* Wfa   = (const float*)d_in[8];
    const float* bfa   = (const float*)d_in[9];
    const float* Wfs   = (const float*)d_in[10];
    const float* bfs   = (const float*)d_in[11];
    const float* Wfp   = (const float*)d_in[12];
    const float* bfp   = (const float*)d_in[13];

    float* ws = (float*)d_ws;
    unsigned short* wh    = (unsigned short*)(ws + WS_WH);
    unsigned*       hmaxk = (unsigned*)(ws + WS_HMAXK);
    float*    hsel   = ws + WS_HSEL;
    float*    gi     = ws + WS_GI;
    float*    hbuf   = ws + WS_HBUF;
    float*    v      = ws + WS_V;
    float*    hs     = ws + WS_HS;
    float*    scal   = ws + WS_SCAL;
    unsigned* cnt    = (unsigned*)(ws + WS_CNT);
    float*    logits = ws + WS_LOGITS;
    float*    out    = (float*)d_out;

    k_prep<<<(128 * FP2 + 255) / 256, 256, 0, stream>>>(Wfa, wh, hmaxk, cnt);
    k_big <<<L * 256, 256, 0, stream>>>(nb, wh, bfa, aid, hmaxk, hsel);
    k_gi  <<<(L * 3 * H + 255) / 256, 256, 0, stream>>>(Wih, bih, pn, hmaxk, hsel, gi);
    k_gru <<<GRU_BLOCKS, 256, 0, stream>>>(Whh, bhh, gi, query, hbuf, cnt);

    const float* qt = hbuf + ((L - 1) & 1) * H;   // hbuf[1]
    k_final1<<<1, 512, 0, stream>>>(qt, Wfs, bfs, Wfp, bfp, bfa, hmaxk, hs, scal, logits);
    k_final2<<<(F + 127) / 128, 128, 0, stream>>>(hs, Wfa, v);
    k_uks  <<<N / 4, 256, 0, stream>>>(nb + (long)(L - 1) * N * F, v, scal, logits);

    k_sm12<<<1, 1024, 0, stream>>>(logits, scal);
    k_sm3 <<<(N + 1 + 255) / 256, 256, 0, stream>>>(logits, scal, out);
}